// Round 11
// baseline (663.706 us; speedup 1.0000x reference)
//
#include <hip/hip_runtime.h>

#define FLTMAX 3.402823466e+38f

// ---------------------------------------------------------------------------
// Geometry:
//   Layer1: B=1024, N=784, Np=896, S=7, F=512, I=8, K=4
//   Layer2: B=1024, N=512, Np=512, S=4, F=10,  I=8, K=4
// Layer-1: R9-proven structure (adaptive s-groups, standalone quant, last
// group folded into finish1). Layer-2 tail rebuilt for occupancy: wide mm2,
// atomic stat2, s-split out2.
// ---------------------------------------------------------------------------

// Fused: xq codes (row in LDS) -> sx1 row sum + bit-packed planes xqbT[i][w][b].
// Also initializes stats1 (consumed only after this dispatch completes).
__global__ void prep1_kernel(const float* __restrict__ x, float* __restrict__ sx1,
                             unsigned* __restrict__ xqbT, unsigned* __restrict__ stats1)
{
    __shared__ float xr[896];
    __shared__ float red[128];
    int b = blockIdx.x;
    if (b == 0) {
        for (int t = threadIdx.x; t < 224; t += 128) {
            stats1[t * 2] = 0x7F7FFFFFu; stats1[t * 2 + 1] = 0u;
        }
    }
    float psum = 0.f;
    for (int n = threadIdx.x; n < 896; n += 128) {
        float v = 0.f;
        if (n < 784) {
            float xv = x[b * 784 + n];
            xv = fminf(fmaxf(xv, 0.f), 1.f);
            v = rintf(__fmul_rn(xv, 255.f));
        }
        xr[n] = v;
        psum += v;  // integer-valued, exact in any order
    }
    red[threadIdx.x] = psum;
    __syncthreads();
    for (int w = 64; w >= 1; w >>= 1) {
        if (threadIdx.x < w) red[threadIdx.x] += red[threadIdx.x + w];
        __syncthreads();
    }
    if (threadIdx.x == 0) sx1[b] = red[0];
    if (threadIdx.x < 28) {
        int w = threadIdx.x;
        unsigned words[8] = {0, 0, 0, 0, 0, 0, 0, 0};
#pragma unroll 8
        for (int n = 0; n < 32; ++n) {
            int v = (int)xr[w * 32 + n];
#pragma unroll
            for (int i = 0; i < 8; ++i) words[i] |= ((unsigned)((v >> i) & 1)) << n;
        }
#pragma unroll
        for (int i = 0; i < 8; ++i) xqbT[(i * 28 + w) * 1024 + b] = words[i];
    }
}

// Fused conductance-prep + transpose: writes g1t[n][k*512+f] directly.
__global__ void prepg1t_kernel(const float* __restrict__ w1, const float* __restrict__ noise1,
                               float* __restrict__ g1t)
{
    __shared__ float t[4][32][33];
    const int n0 = blockIdx.x * 32, f0 = blockIdx.y * 32;
    const int tid = threadIdx.x;
    {
        int n = tid & 31, fi = tid >> 5;
#pragma unroll
        for (int p = 0; p < 4; ++p) {
            int f = p * 8 + fi;
            int gn = n0 + n, gf = f0 + f;
            float gv[4] = {0.f, 0.f, 0.f, 0.f};
            if (gn < 784) {
                float w = w1[gf * 784 + gn];
                float Xi = fminf(fmaxf(rintf(__fmul_rn(__fmul_rn(__fadd_rn(w, 1.f), 0.5f), 255.f)),
                                       0.f), 255.f);
                int xi = (int)Xi;
                float4 nz = *(const float4*)&noise1[(gf * 896 + gn) * 4];
                float nzv[4] = {nz.x, nz.y, nz.z, nz.w};
#pragma unroll
                for (int k = 0; k < 4; ++k) {
                    int slc = (xi >> (2 * k)) & 3;
                    float base = __fadd_rn(__fmul_rn((float)slc, 0.9f), 0.3f);
                    float nf = __fadd_rn(1.f, __fmul_rn(0.05f, nzv[k]));
                    gv[k] = __fmul_rn(base, nf);
                }
            }
#pragma unroll
            for (int k = 0; k < 4; ++k) t[k][n][f] = gv[k];
        }
    }
    __syncthreads();
    {
        int f = tid & 31, nn = tid >> 5;
#pragma unroll
        for (int p = 0; p < 4; ++p) {
            int n = p * 8 + nn;
#pragma unroll
            for (int k = 0; k < 4; ++k)
                g1t[(n0 + n) * 2048 + k * 512 + f0 + f] = t[k][n][f];
        }
    }
}

// Layer-1 dummy column from transposed bit-planes: D = 0.3*popc(128 bits).
__global__ void dqpopT_kernel(const unsigned* __restrict__ xqbT, float* __restrict__ Dq)
{
    __shared__ float red[512];
    const int i = blockIdx.x / 7, s = blockIdx.x % 7;
    const int tid = threadIdx.x;
    float D[4];
    float mn = FLTMAX, mx = -FLTMAX;
#pragma unroll
    for (int u = 0; u < 4; ++u) {
        int b = tid + u * 256;
        int c = 0;
#pragma unroll
        for (int w = 0; w < 4; ++w)
            c += __popc(xqbT[(i * 28 + s * 4 + w) * 1024 + b]);
        D[u] = __fmul_rn((float)c, 0.3f);
        mn = fminf(mn, D[u]);
        mx = fmaxf(mx, D[u]);
    }
    red[tid] = mn; red[256 + tid] = mx;
    __syncthreads();
    for (int w = 128; w >= 1; w >>= 1) {
        if (tid < w) {
            red[tid] = fminf(red[tid], red[tid + w]);
            red[256 + tid] = fmaxf(red[256 + tid], red[256 + tid + w]);
        }
        __syncthreads();
    }
    mn = red[0]; mx = red[256];
    float step = __fmul_rn(__fsub_rn(mx, mn), 0.03125f);
    if (step <= 0.f) step = 1.f;
#pragma unroll
    for (int u = 0; u < 4; ++u) {
        int b = tid + u * 256;
        float idx = fminf(fmaxf(floorf(__fdiv_rn(__fsub_rn(D[u], mn), step)), 0.f), 31.f);
        Dq[(i * 7 + s) * 1024 + b] = __fadd_rn(__fmul_rn(idx, step), mn);
    }
}

// ---------------------------------------------------------------------------
// Layer-1 GEMM, s-grouped: grid.x = Gc*64 (sl, i, b-tile), grid.y = 16 (cols).
// 128x128 tile, BK=32, 8x8 acc/thread; A from bit-packed words, B in LDS.
// Per-element chain: fmaf over n ascending (bit-exact vs R1..R9).
// ---------------------------------------------------------------------------
#define BK 32
__global__ __launch_bounds__(256, 4) void mm1_kernel(
    const unsigned* __restrict__ xqbT, const float* __restrict__ g1t,
    float* __restrict__ P, unsigned* __restrict__ stats, int s0)
{
    __shared__ __align__(16) float Bs[BK][132];
    __shared__ unsigned Abits[128];
    __shared__ float red[512];
    const int tid = threadIdx.x;
    const int sl = blockIdx.x >> 6;
    const int r = blockIdx.x & 63;
    const int i = r >> 3;
    const int b0 = (r & 7) * 128;
    const int s = s0 + sl;
    const int colBase = blockIdx.y * 128;       // [0, 2048)
    const int tx = tid & 15, ty = tid >> 4;

    const int aB = tid >> 5;          // 0..7  (B rows: u*8 + aB)
    const int eB = (tid & 31) << 2;   // 0..124

    // prefetch chunk 0  (xqbT layout: [i][w][b], w = s*4 + chunk)
    float4 pB[4];
    unsigned pAw = 0;
#pragma unroll
    for (int u = 0; u < 4; ++u)
        pB[u] = *(const float4*)&g1t[(s * 128 + u * 8 + aB) * 2048 + colBase + eB];
    if (tid < 128) pAw = xqbT[(i * 28 + s * 4) * 1024 + b0 + tid];

    float acc[8][8] = {};

    for (int ac = 0; ac < 4; ++ac) {
        __syncthreads();
#pragma unroll
        for (int u = 0; u < 4; ++u)
            *(float4*)&Bs[u * 8 + aB][eB] = pB[u];
        if (tid < 128) Abits[tid] = pAw;
        __syncthreads();

        if (ac < 3) {
            const int n0 = s * 128 + (ac + 1) * BK;
#pragma unroll
            for (int u = 0; u < 4; ++u)
                pB[u] = *(const float4*)&g1t[(n0 + u * 8 + aB) * 2048 + colBase + eB];
            if (tid < 128) pAw = xqbT[(i * 28 + s * 4 + ac + 1) * 1024 + b0 + tid];
        }

        unsigned wrd[8];
#pragma unroll
        for (int u = 0; u < 4; ++u) {
            wrd[u]     = Abits[(ty << 2) + u];
            wrd[4 + u] = Abits[64 + (ty << 2) + u];
        }

#pragma unroll 4
        for (int a = 0; a < BK; ++a) {
            float br[8];
            *(float4*)&br[0] = *(const float4*)&Bs[a][(tx << 2)];
            *(float4*)&br[4] = *(const float4*)&Bs[a][64 + (tx << 2)];
#pragma unroll
            for (int u = 0; u < 8; ++u) {
                float ab = (float)((wrd[u] >> a) & 1u);
#pragma unroll
                for (int v = 0; v < 8; ++v)
                    acc[u][v] = fmaf(ab, br[v], acc[u][v]);
            }
        }
    }

    // store P: rows (sl*8+i)*1024 + b0 + uh*64 + ty*4 + u
#pragma unroll
    for (int uh = 0; uh < 2; ++uh)
#pragma unroll
        for (int u = 0; u < 4; ++u) {
            int row = (sl * 8 + i) * 1024 + b0 + uh * 64 + (ty << 2) + u;
#pragma unroll
            for (int vh = 0; vh < 2; ++vh) {
                float4 v = make_float4(acc[uh * 4 + u][vh * 4 + 0], acc[uh * 4 + u][vh * 4 + 1],
                                       acc[uh * 4 + u][vh * 4 + 2], acc[uh * 4 + u][vh * 4 + 3]);
                *(float4*)&P[(size_t)row * 2048 + colBase + vh * 64 + (tx << 2)] = v;
            }
        }

    float mn = acc[0][0], mx = acc[0][0];
#pragma unroll
    for (int u = 0; u < 8; ++u)
#pragma unroll
        for (int v = 0; v < 8; ++v) { mn = fminf(mn, acc[u][v]); mx = fmaxf(mx, acc[u][v]); }
    red[tid] = mn; red[256 + tid] = mx;
    __syncthreads();
    for (int w = 128; w >= 1; w >>= 1) {
        if (tid < w) {
            red[tid] = fminf(red[tid], red[tid + w]);
            red[256 + tid] = fmaxf(red[256 + tid], red[256 + tid + w]);
        }
        __syncthreads();
    }
    if (tid == 0) {
        int k = colBase >> 9;
        int slot = ((s * 8 + i) * 4 + k) * 2;
        atomicMin(&stats[slot], __float_as_uint(red[0]));      // P >= 0: uint order == float order
        atomicMax(&stats[slot + 1], __float_as_uint(red[256]));
    }
}

// ADC-quantize G s-planes and fold into acc1 with the exact original chain:
// for s ascending: acc1 += (i-outer, k-inner fmaf chain). first => acc1 = .
__global__ void quant1_kernel(const float* __restrict__ P, const unsigned* __restrict__ stats,
                              float* __restrict__ acc1, int s0, int G, int first)
{
    int gid = blockIdx.x * 256 + threadIdx.x;  // 131072
    int b = gid >> 7, f4 = gid & 127;
    float4 accR;
    if (first) accR = make_float4(0.f, 0.f, 0.f, 0.f);
    else       accR = *(const float4*)&acc1[(b << 9) + (f4 << 2)];
    for (int sl = 0; sl < G; ++sl) {
        int s = s0 + sl;
        float4 sum = make_float4(0.f, 0.f, 0.f, 0.f);
        for (int i = 0; i < 8; ++i) {
#pragma unroll
            for (int k = 0; k < 4; ++k) {
                int slot = ((s * 8 + i) * 4 + k) * 2;
                float mn = __uint_as_float(stats[slot]);
                float mx = __uint_as_float(stats[slot + 1]);
                float step = __fmul_rn(__fsub_rn(mx, mn), 0.03125f);
                if (step <= 0.f) step = 1.f;
                float4 val = *(const float4*)&P[(size_t)((sl * 8 + i) * 1024 + b) * 2048
                                                + (k << 9) + (f4 << 2)];
                float sc = (float)(1 << (i + 2 * k));
                float ix, pq;
                ix = fminf(fmaxf(floorf(__fdiv_rn(__fsub_rn(val.x, mn), step)), 0.f), 31.f);
                pq = __fadd_rn(__fmul_rn(ix, step), mn); sum.x = fmaf(pq, sc, sum.x);
                ix = fminf(fmaxf(floorf(__fdiv_rn(__fsub_rn(val.y, mn), step)), 0.f), 31.f);
                pq = __fadd_rn(__fmul_rn(ix, step), mn); sum.y = fmaf(pq, sc, sum.y);
                ix = fminf(fmaxf(floorf(__fdiv_rn(__fsub_rn(val.z, mn), step)), 0.f), 31.f);
                pq = __fadd_rn(__fmul_rn(ix, step), mn); sum.z = fmaf(pq, sc, sum.z);
                ix = fminf(fmaxf(floorf(__fdiv_rn(__fsub_rn(val.w, mn), step)), 0.f), 31.f);
                pq = __fadd_rn(__fmul_rn(ix, step), mn); sum.w = fmaf(pq, sc, sum.w);
            }
        }
        accR.x = __fadd_rn(accR.x, sum.x);
        accR.y = __fadd_rn(accR.y, sum.y);
        accR.z = __fadd_rn(accR.z, sum.z);
        accR.w = __fadd_rn(accR.w, sum.w);
    }
    *(float4*)&acc1[(b << 9) + (f4 << 2)] = accR;
}

// finish1: inline-quant the LAST s-group (continuing the exact chain), add to
// acc1 partial, subtract inline dterm1, tanh -> xq2 codes; emits layer-2
// bit-planes xqb2 via ballot and sx2 row sum. Block per b, 512 threads.
__global__ void finish1_kernel(const float* __restrict__ acc1, const float* __restrict__ P,
                               const unsigned* __restrict__ stats, int s0, int G, int first,
                               const float* __restrict__ Dq1, const float* __restrict__ sx1,
                               float* __restrict__ xq2, unsigned* __restrict__ xqb2,
                               float* __restrict__ sx2)
{
    __shared__ float red[512];
    __shared__ float dt;
    int b = blockIdx.x;
    int f = threadIdx.x;                      // 0..511
    if (f == 0) {
        float s = 0.f;
        for (int i = 0; i < 8; ++i) {
            float sc = (float)(85 << i);
            for (int ss = 0; ss < 7; ++ss) s = fmaf(Dq1[(i * 7 + ss) * 1024 + b], sc, s);
        }
        dt = s;
    }
    __syncthreads();
    int gid = b * 512 + f;
    float accR = first ? 0.f : acc1[gid];
    for (int sl = 0; sl < G; ++sl) {
        int s = s0 + sl;
        float sum = 0.f;
        for (int i = 0; i < 8; ++i) {
#pragma unroll
            for (int k = 0; k < 4; ++k) {
                int slot = ((s * 8 + i) * 4 + k) * 2;
                float mn = __uint_as_float(stats[slot]);
                float mx = __uint_as_float(stats[slot + 1]);
                float step = __fmul_rn(__fsub_rn(mx, mn), 0.03125f);
                if (step <= 0.f) step = 1.f;
                float val = P[(size_t)((sl * 8 + i) * 1024 + b) * 2048 + (k << 9) + f];
                float ix = fminf(fmaxf(floorf(__fdiv_rn(__fsub_rn(val, mn), step)), 0.f), 31.f);
                float pq = __fadd_rn(__fmul_rn(ix, step), mn);
                sum = fmaf(pq, (float)(1 << (i + 2 * k)), sum);
            }
        }
        accR = __fadd_rn(accR, sum);
    }
    float total = __fsub_rn(accR, dt);
    float acc = __fdiv_rn(total, 0.9f);
    float o = __fsub_rn(__fdiv_rn(__fmul_rn(2.f, acc), 65025.f), __fdiv_rn(sx1[b], 255.f));
    float h = tanhf(o);
    h = fminf(fmaxf(h, 0.f), 1.f);
    float code = rintf(__fmul_rn(h, 255.f));
    xq2[gid] = code;
    int ci = (int)code;
    int lane = f & 63;
#pragma unroll
    for (int i = 0; i < 8; ++i) {
        unsigned long long m = __ballot((ci >> i) & 1);
        if ((lane & 31) == 0) {
            unsigned wv = (lane & 32) ? (unsigned)(m >> 32) : (unsigned)m;
            xqb2[(i * 1024 + b) * 16 + (f >> 5)] = wv;
        }
    }
    red[f] = code;
    __syncthreads();
    for (int w = 256; w >= 1; w >>= 1) {
        if (f < w) red[f] += red[f + w];
        __syncthreads();
    }
    if (f == 0) sx2[b] = red[0];
}

// Merged layer-2 prep: blocks 0..19 build g2t; blocks 20..51 run dqpop for
// xqb2 (block 20 also inits stats2u for the atomic stat2).
__global__ void prep2_kernel(const float* __restrict__ w3, const float* __restrict__ noise3,
                             float* __restrict__ g2t, const unsigned* __restrict__ xqb2,
                             float* __restrict__ Dq2, unsigned* __restrict__ stats2u)
{
    __shared__ float red[512];
    const int tid = threadIdx.x;
    if (blockIdx.x < 20) {
        int gid = blockIdx.x * 256 + tid;
        if (gid >= 10 * 512) return;
        int f = gid / 512, n = gid % 512;
        float w = w3[f * 512 + n];
        float Xi = fminf(fmaxf(rintf(__fmul_rn(__fmul_rn(__fadd_rn(w, 1.f), 0.5f), 255.f)),
                               0.f), 255.f);
        int xi = (int)Xi;
#pragma unroll
        for (int k = 0; k < 4; ++k) {
            int slc = (xi >> (2 * k)) & 3;
            float base = __fadd_rn(__fmul_rn((float)slc, 0.9f), 0.3f);
            float nf = __fadd_rn(1.f, __fmul_rn(0.05f, noise3[(f * 512 + n) * 4 + k]));
            g2t[n * 40 + k * 10 + f] = __fmul_rn(base, nf);
        }
        return;
    }
    const int q = blockIdx.x - 20;              // 0..31
    if (q == 0) stats2u[tid] = (tid & 1) ? 0u : 0x7F7FFFFFu;   // 128 (mn,mx) pairs
    const int i = q >> 2, s = q & 3;
    float D[4];
    float mn = FLTMAX, mx = -FLTMAX;
#pragma unroll
    for (int u = 0; u < 4; ++u) {
        int b = tid + u * 256;
        uint4 w = *(const uint4*)&xqb2[(i * 1024 + b) * 16 + s * 4];
        int c = __popc(w.x) + __popc(w.y) + __popc(w.z) + __popc(w.w);
        D[u] = __fmul_rn((float)c, 0.3f);
        mn = fminf(mn, D[u]);
        mx = fmaxf(mx, D[u]);
    }
    red[tid] = mn; red[256 + tid] = mx;
    __syncthreads();
    for (int w = 128; w >= 1; w >>= 1) {
        if (tid < w) {
            red[tid] = fminf(red[tid], red[tid + w]);
            red[256 + tid] = fmaxf(red[256 + tid], red[256 + tid + w]);
        }
        __syncthreads();
    }
    mn = red[0]; mx = red[256];
    float step = __fmul_rn(__fsub_rn(mx, mn), 0.03125f);
    if (step <= 0.f) step = 1.f;
#pragma unroll
    for (int u = 0; u < 4; ++u) {
        int b = tid + u * 256;
        float idx = fminf(fmaxf(floorf(__fdiv_rn(__fsub_rn(D[u], mn), step)), 0.f), 31.f);
        Dq2[(i * 4 + s) * 1024 + b] = __fadd_rn(__fmul_rn(idx, step), mn);
    }
}

// Layer-2 matmul, wide: thread per (s,i,b,f) = 327680 threads; 4 k-accs each.
// Per-P2-value chain: fmaf over a ascending (bit-identical to R9's mm2).
__global__ void mm2_kernel(const float* __restrict__ xq2, const float* __restrict__ g2t,
                           float* __restrict__ P2)
{
    int gid = blockIdx.x * 256 + threadIdx.x;   // 327680 exactly
    int f = gid % 10;
    int b = (gid / 10) & 1023;
    int si = gid / 10240;                       // 0..31
    int i = si & 7, s = si >> 3;
    float a0 = 0.f, a1 = 0.f, a2 = 0.f, a3 = 0.f;
    const float* xrow = &xq2[b * 512 + s * 128];
    const float* grow = &g2t[s * 128 * 40];
    for (int a4 = 0; a4 < 128; a4 += 4) {
        float4 xv = *(const float4*)&xrow[a4];
        const float* g = &grow[a4 * 40];
        float bi;
        bi = (float)((((int)xv.x) >> i) & 1);
        a0 = fmaf(bi, g[f], a0);       a1 = fmaf(bi, g[10 + f], a1);
        a2 = fmaf(bi, g[20 + f], a2);  a3 = fmaf(bi, g[30 + f], a3);
        bi = (float)((((int)xv.y) >> i) & 1);
        a0 = fmaf(bi, g[40 + f], a0);  a1 = fmaf(bi, g[50 + f], a1);
        a2 = fmaf(bi, g[60 + f], a2);  a3 = fmaf(bi, g[70 + f], a3);
        bi = (float)((((int)xv.z) >> i) & 1);
        a0 = fmaf(bi, g[80 + f], a0);  a1 = fmaf(bi, g[90 + f], a1);
        a2 = fmaf(bi, g[100 + f], a2); a3 = fmaf(bi, g[110 + f], a3);
        bi = (float)((((int)xv.w) >> i) & 1);
        a0 = fmaf(bi, g[120 + f], a0); a1 = fmaf(bi, g[130 + f], a1);
        a2 = fmaf(bi, g[140 + f], a2); a3 = fmaf(bi, g[150 + f], a3);
    }
    size_t base = (size_t)((s * 8 + i) * 4) * 10240 + b * 10 + f;
    P2[base]             = a0;
    P2[base + 10240]     = a1;
    P2[base + 2 * 10240] = a2;
    P2[base + 3 * 10240] = a3;
}

// stat2, wide: 4 blocks per plane, uint atomics (P2 >= 0).
__global__ void stat2_kernel(const float* __restrict__ P2, unsigned* __restrict__ stats2u)
{
    __shared__ float red[512];
    int p = blockIdx.x >> 2, q = blockIdx.x & 3;
    int tid = threadIdx.x;
    float mn = FLTMAX, mx = -FLTMAX;
    for (int t = tid; t < 2560; t += 256) {
        float v = P2[(size_t)p * 10240 + q * 2560 + t];
        mn = fminf(mn, v); mx = fmaxf(mx, v);
    }
    red[tid] = mn; red[256 + tid] = mx;
    __syncthreads();
    for (int w = 128; w >= 1; w >>= 1) {
        if (tid < w) {
            red[tid] = fminf(red[tid], red[tid + w]);
            red[256 + tid] = fmaxf(red[256 + tid], red[256 + tid + w]);
        }
        __syncthreads();
    }
    if (tid == 0) {
        atomicMin(&stats2u[p * 2], __float_as_uint(red[0]));
        atomicMax(&stats2u[p * 2 + 1], __float_as_uint(red[256]));
    }
}

// out2a: per (s,b,f) quantized partial (i-outer, k-inner fmaf chain, exact).
__global__ void out2a_kernel(const float* __restrict__ P2, const unsigned* __restrict__ stats2u,
                             float* __restrict__ part)
{
    int gid = blockIdx.x * 256 + threadIdx.x;   // 40960
    if (gid >= 40960) return;
    int bf = gid % 10240, s = gid / 10240;
    float sum = 0.f;
    for (int i = 0; i < 8; ++i)
#pragma unroll
        for (int k = 0; k < 4; ++k) {
            int p = (s * 8 + i) * 4 + k;
            float mn = __uint_as_float(stats2u[p * 2]);
            float mx = __uint_as_float(stats2u[p * 2 + 1]);
            float step = __fmul_rn(__fsub_rn(mx, mn), 0.03125f);
            if (step <= 0.f) step = 1.f;
            float val = P2[(size_t)p * 10240 + bf];
            float ix = fminf(fmaxf(floorf(__fdiv_rn(__fsub_rn(val, mn), step)), 0.f), 31.f);
            float pq = __fadd_rn(__fmul_rn(ix, step), mn);
            sum = fmaf(pq, (float)(1 << (i + 2 * k)), sum);
        }
    part[s * 10240 + bf] = sum;
}

// out2b: combine s-partials (s ascending), subtract inline dterm2, finish.
__global__ void out2b_kernel(const float* __restrict__ part, const float* __restrict__ Dq2,
                             const float* __restrict__ sx2, float* __restrict__ out)
{
    int gid = blockIdx.x * 256 + threadIdx.x;   // 10240
    if (gid >= 10240) return;
    int b = gid / 10;
    float dt = 0.f;
    for (int i = 0; i < 8; ++i) {
        float sc = (float)(85 << i);
        for (int s = 0; s < 4; ++s) dt = fmaf(Dq2[(i * 4 + s) * 1024 + b], sc, dt);
    }
    float sum = part[gid];
    sum = __fadd_rn(sum, part[10240 + gid]);
    sum = __fadd_rn(sum, part[2 * 10240 + gid]);
    sum = __fadd_rn(sum, part[3 * 10240 + gid]);
    float total = __fsub_rn(sum, dt);
    float acc = __fdiv_rn(total, 0.9f);
    out[gid] = __fsub_rn(__fdiv_rn(__fmul_rn(2.f, acc), 65025.f), __fdiv_rn(sx2[b], 255.f));
}

extern "C" void kernel_launch(void* const* d_in, const int* in_sizes, int n_in,
                              void* d_out, int out_size, void* d_ws, size_t ws_size,
                              hipStream_t stream)
{
    const float* x      = (const float*)d_in[0];
    const float* w1     = (const float*)d_in[1];
    const float* w3     = (const float*)d_in[2];
    const float* noise1 = (const float*)d_in[3];
    const float* noise3 = (const float*)d_in[4];
    float* out = (float*)d_out;
    float* ws  = (float*)d_ws;

    // ws layout (float offsets) — identical footprint to R9
    float*    g1t    = ws + 0;         // 896*2048  (dead after mm1 -> reused as part)
    float*    part   = ws + 0;         // 4*10240 (alias; used only after finish1)
    float*    acc1   = ws + 1835008;   // 1024*512
    float*    xq2    = ws + 2359296;   // 1024*512
    float*    P2     = ws + 2883584;   // 128*10240
    float*    g2t    = ws + 4194304;   // 512*40
    float*    Dq1    = ws + 4214784;   // 56*1024
    float*    Dq2    = ws + 4272128;   // 32*1024
    float*    sx1    = ws + 4304896;   // 1024
    float*    sx2    = ws + 4305920;   // 1024
    unsigned* stats2u = (unsigned*)(ws + 4306944); // 128 pairs (256 words)
    unsigned* stats1 = (unsigned*)(ws + 4307200); // 224*2 (pad to 512)
    unsigned* xqbT   = (unsigned*)(ws + 4307712); // 8*28*1024 words
    unsigned* xqb2   = (unsigned*)(ws + 4537088); // 8*1024*16 words
    float*    Ps     = ws + 4668160;   // G * 8 * 1024 * 2048

    // adaptive group size: as many 67MB P s-planes as ws allows (R9-proven)
    const size_t fixedf = 4668160;
    const size_t planef = 16777216;
    int G = 1;
    while (G < 7 && (fixedf + (size_t)(G + 1) * planef) * sizeof(float) <= ws_size) ++G;

    prep1_kernel<<<1024, 128, 0, stream>>>(x, sx1, xqbT, stats1);
    prepg1t_kernel<<<dim3(28, 16), 256, 0, stream>>>(w1, noise1, g1t);
    dqpopT_kernel<<<56, 256, 0, stream>>>(xqbT, Dq1);

    int lastS0 = 0, lastG = 7, anyQuant = 0;
    for (int s0 = 0; s0 < 7;) {
        int Gc = (7 - s0 < G) ? (7 - s0) : G;
        mm1_kernel<<<dim3(Gc * 64, 16), 256, 0, stream>>>(xqbT, g1t, Ps, stats1, s0);
        if (s0 + Gc < 7) {
            quant1_kernel<<<512, 256, 0, stream>>>(Ps, stats1, acc1, s0, Gc, s0 == 0);
            anyQuant = 1;
        } else {
            lastS0 = s0; lastG = Gc;
        }
        s0 += Gc;
    }

    finish1_kernel<<<1024, 512, 0, stream>>>(acc1, Ps, stats1, lastS0, lastG,
                                             anyQuant ? 0 : 1, Dq1, sx1, xq2, xqb2, sx2);

    prep2_kernel<<<52, 256, 0, stream>>>(w3, noise3, g2t, xqb2, Dq2, stats2u);
    mm2_kernel<<<1280, 256, 0, stream>>>(xq2, g2t, P2);
    stat2_kernel<<<512, 256, 0, stream>>>(P2, stats2u);
    out2a_kernel<<<160, 256, 0, stream>>>(P2, stats2u, part);
    out2b_kernel<<<40, 256, 0, stream>>>(part, Dq2, sx2, out);
}

// Round 13
// 637.807 us; speedup vs baseline: 1.0406x; 1.0406x over previous
//
#include <hip/hip_runtime.h>

#define FLTMAX 3.402823466e+38f

typedef float vfloat4 __attribute__((ext_vector_type(4)));  // nontemporal-legal

// ---------------------------------------------------------------------------
// Geometry:
//   Layer1: B=1024, N=784, Np=896, S=7, F=512, I=8, K=4
//   Layer2: B=1024, N=512, Np=512, S=4, F=10,  I=8, K=4
// Layer-1: R9-proven structure (adaptive s-groups, standalone quant, last
// group folded into finish1). R13: quant/finish P reads software-pipelined
// (i+1 preload) + nontemporal — ~2x memory-level parallelism on the 470 MB
// of stream-once P traffic. Chains unchanged (bit-exact).
// ---------------------------------------------------------------------------

// Fused: xq codes (row in LDS) -> sx1 row sum + bit-packed planes xqbT[i][w][b].
// Also initializes stats1 (consumed only after this dispatch completes).
__global__ void prep1_kernel(const float* __restrict__ x, float* __restrict__ sx1,
                             unsigned* __restrict__ xqbT, unsigned* __restrict__ stats1)
{
    __shared__ float xr[896];
    __shared__ float red[128];
    int b = blockIdx.x;
    if (b == 0) {
        for (int t = threadIdx.x; t < 224; t += 128) {
            stats1[t * 2] = 0x7F7FFFFFu; stats1[t * 2 + 1] = 0u;
        }
    }
    float psum = 0.f;
    for (int n = threadIdx.x; n < 896; n += 128) {
        float v = 0.f;
        if (n < 784) {
            float xv = x[b * 784 + n];
            xv = fminf(fmaxf(xv, 0.f), 1.f);
            v = rintf(__fmul_rn(xv, 255.f));
        }
        xr[n] = v;
        psum += v;  // integer-valued, exact in any order
    }
    red[threadIdx.x] = psum;
    __syncthreads();
    for (int w = 64; w >= 1; w >>= 1) {
        if (threadIdx.x < w) red[threadIdx.x] += red[threadIdx.x + w];
        __syncthreads();
    }
    if (threadIdx.x == 0) sx1[b] = red[0];
    if (threadIdx.x < 28) {
        int w = threadIdx.x;
        unsigned words[8] = {0, 0, 0, 0, 0, 0, 0, 0};
#pragma unroll 8
        for (int n = 0; n < 32; ++n) {
            int v = (int)xr[w * 32 + n];
#pragma unroll
            for (int i = 0; i < 8; ++i) words[i] |= ((unsigned)((v >> i) & 1)) << n;
        }
#pragma unroll
        for (int i = 0; i < 8; ++i) xqbT[(i * 28 + w) * 1024 + b] = words[i];
    }
}

// Fused conductance-prep + transpose: writes g1t[n][k*512+f] directly.
__global__ void prepg1t_kernel(const float* __restrict__ w1, const float* __restrict__ noise1,
                               float* __restrict__ g1t)
{
    __shared__ float t[4][32][33];
    const int n0 = blockIdx.x * 32, f0 = blockIdx.y * 32;
    const int tid = threadIdx.x;
    {
        int n = tid & 31, fi = tid >> 5;
#pragma unroll
        for (int p = 0; p < 4; ++p) {
            int f = p * 8 + fi;
            int gn = n0 + n, gf = f0 + f;
            float gv[4] = {0.f, 0.f, 0.f, 0.f};
            if (gn < 784) {
                float w = w1[gf * 784 + gn];
                float Xi = fminf(fmaxf(rintf(__fmul_rn(__fmul_rn(__fadd_rn(w, 1.f), 0.5f), 255.f)),
                                       0.f), 255.f);
                int xi = (int)Xi;
                float4 nz = *(const float4*)&noise1[(gf * 896 + gn) * 4];
                float nzv[4] = {nz.x, nz.y, nz.z, nz.w};
#pragma unroll
                for (int k = 0; k < 4; ++k) {
                    int slc = (xi >> (2 * k)) & 3;
                    float base = __fadd_rn(__fmul_rn((float)slc, 0.9f), 0.3f);
                    float nf = __fadd_rn(1.f, __fmul_rn(0.05f, nzv[k]));
                    gv[k] = __fmul_rn(base, nf);
                }
            }
#pragma unroll
            for (int k = 0; k < 4; ++k) t[k][n][f] = gv[k];
        }
    }
    __syncthreads();
    {
        int f = tid & 31, nn = tid >> 5;
#pragma unroll
        for (int p = 0; p < 4; ++p) {
            int n = p * 8 + nn;
#pragma unroll
            for (int k = 0; k < 4; ++k)
                g1t[(n0 + n) * 2048 + k * 512 + f0 + f] = t[k][n][f];
        }
    }
}

// g2t[n][k][f] layout for layer-2 matmul
__global__ void prepg2_kernel(const float* __restrict__ w3, const float* __restrict__ noise3,
                              float* __restrict__ g2t)
{
    int gid = blockIdx.x * 256 + threadIdx.x;
    if (gid >= 10 * 512) return;
    int f = gid / 512, n = gid % 512;
    float w = w3[f * 512 + n];
    float Xi = fminf(fmaxf(rintf(__fmul_rn(__fmul_rn(__fadd_rn(w, 1.f), 0.5f), 255.f)),
                           0.f), 255.f);
    int xi = (int)Xi;
#pragma unroll
    for (int k = 0; k < 4; ++k) {
        int slc = (xi >> (2 * k)) & 3;
        float base = __fadd_rn(__fmul_rn((float)slc, 0.9f), 0.3f);
        float nf = __fadd_rn(1.f, __fmul_rn(0.05f, noise3[(f * 512 + n) * 4 + k]));
        g2t[n * 40 + k * 10 + f] = __fmul_rn(base, nf);
    }
}

// Layer-1 dummy column from transposed bit-planes: D = 0.3*popc(128 bits).
__global__ void dqpopT_kernel(const unsigned* __restrict__ xqbT, float* __restrict__ Dq)
{
    __shared__ float red[512];
    const int i = blockIdx.x / 7, s = blockIdx.x % 7;
    const int tid = threadIdx.x;
    float D[4];
    float mn = FLTMAX, mx = -FLTMAX;
#pragma unroll
    for (int u = 0; u < 4; ++u) {
        int b = tid + u * 256;
        int c = 0;
#pragma unroll
        for (int w = 0; w < 4; ++w)
            c += __popc(xqbT[(i * 28 + s * 4 + w) * 1024 + b]);
        D[u] = __fmul_rn((float)c, 0.3f);
        mn = fminf(mn, D[u]);
        mx = fmaxf(mx, D[u]);
    }
    red[tid] = mn; red[256 + tid] = mx;
    __syncthreads();
    for (int w = 128; w >= 1; w >>= 1) {
        if (tid < w) {
            red[tid] = fminf(red[tid], red[tid + w]);
            red[256 + tid] = fmaxf(red[256 + tid], red[256 + tid + w]);
        }
        __syncthreads();
    }
    mn = red[0]; mx = red[256];
    float step = __fmul_rn(__fsub_rn(mx, mn), 0.03125f);
    if (step <= 0.f) step = 1.f;
#pragma unroll
    for (int u = 0; u < 4; ++u) {
        int b = tid + u * 256;
        float idx = fminf(fmaxf(floorf(__fdiv_rn(__fsub_rn(D[u], mn), step)), 0.f), 31.f);
        Dq[(i * 7 + s) * 1024 + b] = __fadd_rn(__fmul_rn(idx, step), mn);
    }
}

// Layer-2 dummy column from xqb2 ([i][b][16w] layout).
__global__ void dqpop_kernel(const unsigned* __restrict__ xqb, float* __restrict__ Dq,
                             int S, int wpr)
{
    __shared__ float red[512];
    const int i = blockIdx.x / S, s = blockIdx.x % S;
    const int tid = threadIdx.x;
    float D[4];
    float mn = FLTMAX, mx = -FLTMAX;
#pragma unroll
    for (int u = 0; u < 4; ++u) {
        int b = tid + u * 256;
        uint4 w = *(const uint4*)&xqb[(i * 1024 + b) * wpr + s * 4];
        int c = __popc(w.x) + __popc(w.y) + __popc(w.z) + __popc(w.w);
        D[u] = __fmul_rn((float)c, 0.3f);
        mn = fminf(mn, D[u]);
        mx = fmaxf(mx, D[u]);
    }
    red[tid] = mn; red[256 + tid] = mx;
    __syncthreads();
    for (int w = 128; w >= 1; w >>= 1) {
        if (tid < w) {
            red[tid] = fminf(red[tid], red[tid + w]);
            red[256 + tid] = fmaxf(red[256 + tid], red[256 + tid + w]);
        }
        __syncthreads();
    }
    mn = red[0]; mx = red[256];
    float step = __fmul_rn(__fsub_rn(mx, mn), 0.03125f);
    if (step <= 0.f) step = 1.f;
#pragma unroll
    for (int u = 0; u < 4; ++u) {
        int b = tid + u * 256;
        float idx = fminf(fmaxf(floorf(__fdiv_rn(__fsub_rn(D[u], mn), step)), 0.f), 31.f);
        Dq[(i * S + s) * 1024 + b] = __fadd_rn(__fmul_rn(idx, step), mn);
    }
}

// ---------------------------------------------------------------------------
// Layer-1 GEMM, s-grouped: grid.x = Gc*64 (sl, i, b-tile), grid.y = 16 (cols).
// 128x128 tile, BK=32, 8x8 acc/thread; A from bit-packed words, B in LDS.
// Per-element chain: fmaf over n ascending (bit-exact vs R1..R9).
// ---------------------------------------------------------------------------
#define BK 32
__global__ __launch_bounds__(256, 4) void mm1_kernel(
    const unsigned* __restrict__ xqbT, const float* __restrict__ g1t,
    float* __restrict__ P, unsigned* __restrict__ stats, int s0)
{
    __shared__ __align__(16) float Bs[BK][132];
    __shared__ unsigned Abits[128];
    __shared__ float red[512];
    const int tid = threadIdx.x;
    const int sl = blockIdx.x >> 6;
    const int r = blockIdx.x & 63;
    const int i = r >> 3;
    const int b0 = (r & 7) * 128;
    const int s = s0 + sl;
    const int colBase = blockIdx.y * 128;       // [0, 2048)
    const int tx = tid & 15, ty = tid >> 4;

    const int aB = tid >> 5;          // 0..7  (B rows: u*8 + aB)
    const int eB = (tid & 31) << 2;   // 0..124

    // prefetch chunk 0  (xqbT layout: [i][w][b], w = s*4 + chunk)
    float4 pB[4];
    unsigned pAw = 0;
#pragma unroll
    for (int u = 0; u < 4; ++u)
        pB[u] = *(const float4*)&g1t[(s * 128 + u * 8 + aB) * 2048 + colBase + eB];
    if (tid < 128) pAw = xqbT[(i * 28 + s * 4) * 1024 + b0 + tid];

    float acc[8][8] = {};

    for (int ac = 0; ac < 4; ++ac) {
        __syncthreads();
#pragma unroll
        for (int u = 0; u < 4; ++u)
            *(float4*)&Bs[u * 8 + aB][eB] = pB[u];
        if (tid < 128) Abits[tid] = pAw;
        __syncthreads();

        if (ac < 3) {
            const int n0 = s * 128 + (ac + 1) * BK;
#pragma unroll
            for (int u = 0; u < 4; ++u)
                pB[u] = *(const float4*)&g1t[(n0 + u * 8 + aB) * 2048 + colBase + eB];
            if (tid < 128) pAw = xqbT[(i * 28 + s * 4 + ac + 1) * 1024 + b0 + tid];
        }

        unsigned wrd[8];
#pragma unroll
        for (int u = 0; u < 4; ++u) {
            wrd[u]     = Abits[(ty << 2) + u];
            wrd[4 + u] = Abits[64 + (ty << 2) + u];
        }

#pragma unroll 4
        for (int a = 0; a < BK; ++a) {
            float br[8];
            *(float4*)&br[0] = *(const float4*)&Bs[a][(tx << 2)];
            *(float4*)&br[4] = *(const float4*)&Bs[a][64 + (tx << 2)];
#pragma unroll
            for (int u = 0; u < 8; ++u) {
                float ab = (float)((wrd[u] >> a) & 1u);
#pragma unroll
                for (int v = 0; v < 8; ++v)
                    acc[u][v] = fmaf(ab, br[v], acc[u][v]);
            }
        }
    }

    // store P: rows (sl*8+i)*1024 + b0 + uh*64 + ty*4 + u
#pragma unroll
    for (int uh = 0; uh < 2; ++uh)
#pragma unroll
        for (int u = 0; u < 4; ++u) {
            int row = (sl * 8 + i) * 1024 + b0 + uh * 64 + (ty << 2) + u;
#pragma unroll
            for (int vh = 0; vh < 2; ++vh) {
                float4 v = make_float4(acc[uh * 4 + u][vh * 4 + 0], acc[uh * 4 + u][vh * 4 + 1],
                                       acc[uh * 4 + u][vh * 4 + 2], acc[uh * 4 + u][vh * 4 + 3]);
                *(float4*)&P[(size_t)row * 2048 + colBase + vh * 64 + (tx << 2)] = v;
            }
        }

    float mn = acc[0][0], mx = acc[0][0];
#pragma unroll
    for (int u = 0; u < 8; ++u)
#pragma unroll
        for (int v = 0; v < 8; ++v) { mn = fminf(mn, acc[u][v]); mx = fmaxf(mx, acc[u][v]); }
    red[tid] = mn; red[256 + tid] = mx;
    __syncthreads();
    for (int w = 128; w >= 1; w >>= 1) {
        if (tid < w) {
            red[tid] = fminf(red[tid], red[tid + w]);
            red[256 + tid] = fmaxf(red[256 + tid], red[256 + tid + w]);
        }
        __syncthreads();
    }
    if (tid == 0) {
        int k = colBase >> 9;
        int slot = ((s * 8 + i) * 4 + k) * 2;
        atomicMin(&stats[slot], __float_as_uint(red[0]));      // P >= 0: uint order == float order
        atomicMax(&stats[slot + 1], __float_as_uint(red[256]));
    }
}

// ADC-quantize G s-planes and fold into acc1 with the exact original chain:
// for s ascending: acc1 += (i-outer, k-inner fmaf chain). first => acc1 = .
// R13: i+1 preload pipeline + nontemporal loads (values & chain unchanged).
__global__ void quant1_kernel(const float* __restrict__ P, const unsigned* __restrict__ stats,
                              float* __restrict__ acc1, int s0, int G, int first)
{
    int gid = blockIdx.x * 256 + threadIdx.x;  // 131072
    int b = gid >> 7, f4 = gid & 127;
    float4 accR;
    if (first) accR = make_float4(0.f, 0.f, 0.f, 0.f);
    else       accR = *(const float4*)&acc1[(b << 9) + (f4 << 2)];
    for (int sl = 0; sl < G; ++sl) {
        int s = s0 + sl;
        float4 sum = make_float4(0.f, 0.f, 0.f, 0.f);
        vfloat4 v[4], nv[4];
#pragma unroll
        for (int k = 0; k < 4; ++k)
            v[k] = __builtin_nontemporal_load(
                (const vfloat4*)&P[(size_t)((sl * 8) * 1024 + b) * 2048 + (k << 9) + (f4 << 2)]);
        for (int i = 0; i < 8; ++i) {
            if (i < 7) {
#pragma unroll
                for (int k = 0; k < 4; ++k)
                    nv[k] = __builtin_nontemporal_load(
                        (const vfloat4*)&P[(size_t)((sl * 8 + i + 1) * 1024 + b) * 2048
                                           + (k << 9) + (f4 << 2)]);
            }
#pragma unroll
            for (int k = 0; k < 4; ++k) {
                int slot = ((s * 8 + i) * 4 + k) * 2;
                float mn = __uint_as_float(stats[slot]);
                float mx = __uint_as_float(stats[slot + 1]);
                float step = __fmul_rn(__fsub_rn(mx, mn), 0.03125f);
                if (step <= 0.f) step = 1.f;
                float sc = (float)(1 << (i + 2 * k));
                float ix, pq;
                ix = fminf(fmaxf(floorf(__fdiv_rn(__fsub_rn(v[k][0], mn), step)), 0.f), 31.f);
                pq = __fadd_rn(__fmul_rn(ix, step), mn); sum.x = fmaf(pq, sc, sum.x);
                ix = fminf(fmaxf(floorf(__fdiv_rn(__fsub_rn(v[k][1], mn), step)), 0.f), 31.f);
                pq = __fadd_rn(__fmul_rn(ix, step), mn); sum.y = fmaf(pq, sc, sum.y);
                ix = fminf(fmaxf(floorf(__fdiv_rn(__fsub_rn(v[k][2], mn), step)), 0.f), 31.f);
                pq = __fadd_rn(__fmul_rn(ix, step), mn); sum.z = fmaf(pq, sc, sum.z);
                ix = fminf(fmaxf(floorf(__fdiv_rn(__fsub_rn(v[k][3], mn), step)), 0.f), 31.f);
                pq = __fadd_rn(__fmul_rn(ix, step), mn); sum.w = fmaf(pq, sc, sum.w);
            }
#pragma unroll
            for (int k = 0; k < 4; ++k) v[k] = nv[k];
        }
        accR.x = __fadd_rn(accR.x, sum.x);
        accR.y = __fadd_rn(accR.y, sum.y);
        accR.z = __fadd_rn(accR.z, sum.z);
        accR.w = __fadd_rn(accR.w, sum.w);
    }
    *(float4*)&acc1[(b << 9) + (f4 << 2)] = accR;
}

// finish1: inline-quant the LAST s-group (i+1 preload pipeline + nontemporal,
// exact chain), add to acc1 partial, subtract inline dterm1, tanh -> xq2;
// emits layer-2 bit-planes xqb2 via ballot and sx2 row sum. Block per b.
__global__ void finish1_kernel(const float* __restrict__ acc1, const float* __restrict__ P,
                               const unsigned* __restrict__ stats, int s0, int G, int first,
                               const float* __restrict__ Dq1, const float* __restrict__ sx1,
                               float* __restrict__ xq2, unsigned* __restrict__ xqb2,
                               float* __restrict__ sx2)
{
    __shared__ float red[512];
    __shared__ float dt;
    int b = blockIdx.x;
    int f = threadIdx.x;                      // 0..511
    if (f == 0) {
        float s = 0.f;
        for (int i = 0; i < 8; ++i) {
            float sc = (float)(85 << i);
            for (int ss = 0; ss < 7; ++ss) s = fmaf(Dq1[(i * 7 + ss) * 1024 + b], sc, s);
        }
        dt = s;
    }
    __syncthreads();
    int gid = b * 512 + f;
    float accR = first ? 0.f : acc1[gid];
    for (int sl = 0; sl < G; ++sl) {
        int s = s0 + sl;
        float sum = 0.f;
        float v[4], nv[4];
#pragma unroll
        for (int k = 0; k < 4; ++k)
            v[k] = __builtin_nontemporal_load(
                &P[(size_t)((sl * 8) * 1024 + b) * 2048 + (k << 9) + f]);
        for (int i = 0; i < 8; ++i) {
            if (i < 7) {
#pragma unroll
                for (int k = 0; k < 4; ++k)
                    nv[k] = __builtin_nontemporal_load(
                        &P[(size_t)((sl * 8 + i + 1) * 1024 + b) * 2048 + (k << 9) + f]);
            }
#pragma unroll
            for (int k = 0; k < 4; ++k) {
                int slot = ((s * 8 + i) * 4 + k) * 2;
                float mn = __uint_as_float(stats[slot]);
                float mx = __uint_as_float(stats[slot + 1]);
                float step = __fmul_rn(__fsub_rn(mx, mn), 0.03125f);
                if (step <= 0.f) step = 1.f;
                float ix = fminf(fmaxf(floorf(__fdiv_rn(__fsub_rn(v[k], mn), step)), 0.f), 31.f);
                float pq = __fadd_rn(__fmul_rn(ix, step), mn);
                sum = fmaf(pq, (float)(1 << (i + 2 * k)), sum);
            }
#pragma unroll
            for (int k = 0; k < 4; ++k) v[k] = nv[k];
        }
        accR = __fadd_rn(accR, sum);
    }
    float total = __fsub_rn(accR, dt);
    float acc = __fdiv_rn(total, 0.9f);
    float o = __fsub_rn(__fdiv_rn(__fmul_rn(2.f, acc), 65025.f), __fdiv_rn(sx1[b], 255.f));
    float h = tanhf(o);
    h = fminf(fmaxf(h, 0.f), 1.f);
    float code = rintf(__fmul_rn(h, 255.f));
    xq2[gid] = code;
    int ci = (int)code;
    int lane = f & 63;
#pragma unroll
    for (int i = 0; i < 8; ++i) {
        unsigned long long m = __ballot((ci >> i) & 1);
        if ((lane & 31) == 0) {
            unsigned wv = (lane & 32) ? (unsigned)(m >> 32) : (unsigned)m;
            xqb2[(i * 1024 + b) * 16 + (f >> 5)] = wv;
        }
    }
    red[f] = code;
    __syncthreads();
    for (int w = 256; w >= 1; w >>= 1) {
        if (f < w) red[f] += red[f + w];
        __syncthreads();
    }
    if (f == 0) sx2[b] = red[0];
}

// Layer-2 matmul: thread per (s,b,f), 32 accumulators (i,k)
__global__ void mm2_kernel(const float* __restrict__ xq2, const float* __restrict__ g2t,
                           float* __restrict__ P2)
{
    int gid = blockIdx.x * 256 + threadIdx.x;  // 40960
    if (gid >= 40960) return;
    int f = gid % 10;
    int b = (gid / 10) & 1023;
    int s = gid / 10240;
    float acc[8][4] = {};
    for (int a = 0; a < 128; ++a) {
        int n = s * 128 + a;
        int xi = (int)xq2[b * 512 + n];
        float g0 = g2t[n * 40 + f];
        float gA = g2t[n * 40 + 10 + f];
        float gB = g2t[n * 40 + 20 + f];
        float gC = g2t[n * 40 + 30 + f];
#pragma unroll
        for (int i = 0; i < 8; ++i) {
            float bi = (float)((xi >> i) & 1);
            acc[i][0] = fmaf(bi, g0, acc[i][0]);
            acc[i][1] = fmaf(bi, gA, acc[i][1]);
            acc[i][2] = fmaf(bi, gB, acc[i][2]);
            acc[i][3] = fmaf(bi, gC, acc[i][3]);
        }
    }
#pragma unroll
    for (int i = 0; i < 8; ++i)
#pragma unroll
        for (int k = 0; k < 4; ++k)
            P2[(size_t)((s * 8 + i) * 4 + k) * 10240 + b * 10 + f] = acc[i][k];
}

__global__ void stat2_kernel(const float* __restrict__ P2, float2* __restrict__ stats2)
{
    __shared__ float red[512];
    int p = blockIdx.x;  // 128 planes
    int tid = threadIdx.x;
    float mn = FLTMAX, mx = -FLTMAX;
    for (int t = tid; t < 10240; t += 256) {
        float v = P2[(size_t)p * 10240 + t];
        mn = fminf(mn, v); mx = fmaxf(mx, v);
    }
    red[tid] = mn; red[256 + tid] = mx;
    __syncthreads();
    for (int w = 128; w >= 1; w >>= 1) {
        if (tid < w) {
            red[tid] = fminf(red[tid], red[tid + w]);
            red[256 + tid] = fmaxf(red[256 + tid], red[256 + tid + w]);
        }
        __syncthreads();
    }
    if (tid == 0) {
        float step = __fmul_rn(__fsub_rn(red[256], red[0]), 0.03125f);
        if (step <= 0.f) step = 1.f;
        stats2[p] = make_float2(red[0], step);
    }
}

// dterm2[b] computed inline per thread (exact i-outer/s-inner chain).
__global__ void out2_kernel(const float* __restrict__ P2, const float2* __restrict__ stats2,
                            const float* __restrict__ Dq2, const float* __restrict__ sx2,
                            float* __restrict__ out)
{
    int gid = blockIdx.x * 256 + threadIdx.x;  // 10240
    if (gid >= 10240) return;
    int b = gid / 10;
    float dt = 0.f;
    for (int i = 0; i < 8; ++i) {
        float sc = (float)(85 << i);
        for (int s = 0; s < 4; ++s) dt = fmaf(Dq2[(i * 4 + s) * 1024 + b], sc, dt);
    }
    float sum = 0.f;
    for (int s = 0; s < 4; ++s)
        for (int i = 0; i < 8; ++i)
#pragma unroll
            for (int k = 0; k < 4; ++k) {
                int p = (s * 8 + i) * 4 + k;
                float2 st = stats2[p];
                float val = P2[(size_t)p * 10240 + gid];
                float idx = fminf(fmaxf(floorf(__fdiv_rn(__fsub_rn(val, st.x), st.y)), 0.f), 31.f);
                float pq = __fadd_rn(__fmul_rn(idx, st.y), st.x);
                sum = fmaf(pq, (float)(1 << (i + 2 * k)), sum);
            }
    float total = __fsub_rn(sum, dt);
    float acc = __fdiv_rn(total, 0.9f);
    out[gid] = __fsub_rn(__fdiv_rn(__fmul_rn(2.f, acc), 65025.f), __fdiv_rn(sx2[b], 255.f));
}

extern "C" void kernel_launch(void* const* d_in, const int* in_sizes, int n_in,
                              void* d_out, int out_size, void* d_ws, size_t ws_size,
                              hipStream_t stream)
{
    const float* x      = (const float*)d_in[0];
    const float* w1     = (const float*)d_in[1];
    const float* w3     = (const float*)d_in[2];
    const float* noise1 = (const float*)d_in[3];
    const float* noise3 = (const float*)d_in[4];
    float* out = (float*)d_out;
    float* ws  = (float*)d_ws;

    // ws layout (float offsets) — identical to R9
    float*    g1t    = ws + 0;         // 896*2048
    float*    acc1   = ws + 1835008;   // 1024*512
    float*    xq2    = ws + 2359296;   // 1024*512
    float*    P2     = ws + 2883584;   // 128*10240
    float*    g2t    = ws + 4194304;   // 512*40
    float*    Dq1    = ws + 4214784;   // 56*1024
    float*    Dq2    = ws + 4272128;   // 32*1024
    float*    sx1    = ws + 4304896;   // 1024
    float*    sx2    = ws + 4305920;   // 1024
    float2*   stats2 = (float2*)(ws + 4306944);   // 128 pairs
    unsigned* stats1 = (unsigned*)(ws + 4307200); // 224*2 (pad to 512)
    unsigned* xqbT   = (unsigned*)(ws + 4307712); // 8*28*1024 words
    unsigned* xqb2   = (unsigned*)(ws + 4537088); // 8*1024*16 words
    float*    Ps     = ws + 4668160;   // G * 8 * 1024 * 2048

    // adaptive group size: as many 67MB P s-planes as ws allows (R9-proven)
    const size_t fixedf = 4668160;
    const size_t planef = 16777216;
    int G = 1;
    while (G < 7 && (fixedf + (size_t)(G + 1) * planef) * sizeof(float) <= ws_size) ++G;

    prep1_kernel<<<1024, 128, 0, stream>>>(x, sx1, xqbT, stats1);
    prepg1t_kernel<<<dim3(28, 16), 256, 0, stream>>>(w1, noise1, g1t);
    dqpopT_kernel<<<56, 256, 0, stream>>>(xqbT, Dq1);

    int lastS0 = 0, lastG = 7, anyQuant = 0;
    for (int s0 = 0; s0 < 7;) {
        int Gc = (7 - s0 < G) ? (7 - s0) : G;
        mm1_kernel<<<dim3(Gc * 64, 16), 256, 0, stream>>>(xqbT, g1t, Ps, stats1, s0);
        if (s0 + Gc < 7) {
            quant1_kernel<<<512, 256, 0, stream>>>(Ps, stats1, acc1, s0, Gc, s0 == 0);
            anyQuant = 1;
        } else {
            lastS0 = s0; lastG = Gc;
        }
        s0 += Gc;
    }

    finish1_kernel<<<1024, 512, 0, stream>>>(acc1, Ps, stats1, lastS0, lastG,
                                             anyQuant ? 0 : 1, Dq1, sx1, xq2, xqb2, sx2);

    prepg2_kernel<<<20, 256, 0, stream>>>(w3, noise3, g2t);
    dqpop_kernel<<<32, 256, 0, stream>>>(xqb2, Dq2, 4, 16);
    mm2_kernel<<<160, 256, 0, stream>>>(xq2, g2t, P2);
    stat2_kernel<<<128, 256, 0, stream>>>(P2, stats2);
    out2_kernel<<<40, 256, 0, stream>>>(P2, stats2, Dq2, sx2, out);
}